// Round 5
// baseline (429.998 us; speedup 1.0000x reference)
//
#include <hip/hip_runtime.h>
#include <hip/hip_bf16.h>
#include <cstddef>
#include <cstdint>

// (B,T,I,H,K) = (32,1024,512,512,2)
#define B_  32
#define T_  1024
#define I_  512
#define H_  512
#define M_  (B_ * T_)     // 32768
#define TP_ 1025          // padded T rows (row 0 = zeros) per batch

typedef __bf16 bf16x8  __attribute__((ext_vector_type(8)));
typedef float  floatx4 __attribute__((ext_vector_type(4)));
typedef unsigned short ushort8v __attribute__((ext_vector_type(8)));

__device__ __forceinline__ unsigned short f2bf(float f) {
    uint32_t u = __float_as_uint(f);
    return (unsigned short)((u + 0x7FFFu + ((u >> 16) & 1u)) >> 16);
}
__device__ __forceinline__ float sigm(float x) {
    return __builtin_amdgcn_rcpf(1.f + __expf(-x));
}

#define GLL(src, dst) __builtin_amdgcn_global_load_lds( \
    (const __attribute__((address_space(1))) void*)(src), \
    (__attribute__((address_space(3))) void*)(dst), 16, 0, 0)

// ---------------------------------------------------------------------------
// Prep: Ab2[b][trow][i] bf16 (trow 0 = zeros, else x[b][trow-1]);
//       Wp[gate][ksub][h][kw] bf16 (kk=ksub*32+kw, tap=kk>>9, i=kk&511).
// 16B stores per thread.
// ---------------------------------------------------------------------------
#define NB_BUILD 8200    // 32*1025*512 / 8 / 256
#define NB_PACK  512     // 2*32*512*32 / 8 / 256

__global__ __launch_bounds__(256) void prep(const float* __restrict__ x,
                                            const float* __restrict__ Wf,
                                            const float* __restrict__ Wz,
                                            unsigned short* __restrict__ Ab2,
                                            unsigned short* __restrict__ Wp) {
    if (blockIdx.x < NB_BUILD) {
        int g = blockIdx.x * 256 + threadIdx.x;     // 2,099,200
        int idx8 = g << 3;
        int row = idx8 >> 9;                        // 0 .. 32*1025-1
        int col = idx8 & 511;
        int b    = (int)((unsigned)row / TP_);
        int trow = row - b * TP_;
        ushort8v o = {0, 0, 0, 0, 0, 0, 0, 0};
        if (trow > 0) {
            const float* src = &x[((size_t)b * T_ + (trow - 1)) * I_ + col];
            float4 v0 = *(const float4*)src;
            float4 v1 = *(const float4*)(src + 4);
            o[0] = f2bf(v0.x); o[1] = f2bf(v0.y); o[2] = f2bf(v0.z); o[3] = f2bf(v0.w);
            o[4] = f2bf(v1.x); o[5] = f2bf(v1.y); o[6] = f2bf(v1.z); o[7] = f2bf(v1.w);
        }
        *(ushort8v*)&Ab2[(size_t)idx8] = o;
    } else {
        int g = (blockIdx.x - NB_BUILD) * 256 + threadIdx.x;  // 131072
        int e8   = g << 3;
        int gate = e8 >> 19;
        int e2   = e8 & 524287;
        int ksub = e2 >> 14;
        int h    = (e2 >> 5) & 511;
        int kw0  = e2 & 31;
        const float* G = gate ? Wz : Wf;
        ushort8v o;
        #pragma unroll
        for (int j = 0; j < 8; ++j) {
            int kk  = ksub * 32 + kw0 + j;
            int tap = kk >> 9;
            int i   = kk & 511;
            o[j] = f2bf(G[h * (I_ * 2) + i * 2 + tap]);
        }
        *(ushort8v*)&Wp[(size_t)e8] = o;
    }
}

// ---------------------------------------------------------------------------
// Fused dual-gate MFMA GEMM + full scan via decoupled lookback.
// vid = atomicAdd order; pos = vid>>7 (t-chunk of 128), chain = vid&127:
// b = chain&31, ni = chain>>5. Chains over pos are deadlock-free because
// vid order == block start order (pred started earlier -> resident/finished).
// Epilogue: sigmoids on fp32 accs (kept in regs), 4t-segment affines -> LDS,
// block affine per h, lookback publish, replay tile, write d_out directly.
// ---------------------------------------------------------------------------
__global__ __launch_bounds__(256, 2) void mfma_gemm_scan(
        const unsigned short* __restrict__ Ab2,  // [32][1025][512]
        const unsigned short* __restrict__ Wp,   // [2][32][512][32]
        const float* __restrict__ biasF,
        const float* __restrict__ biasZ,
        float* __restrict__ out,                 // [M_][512] fp32
        float* __restrict__ Hpub,                // [8][128][128]
        uint32_t* __restrict__ flags,            // [8][128]
        uint32_t* __restrict__ counter) {
    // K-loop: per sub-stage s (s*12288 shorts): A[0,4096) BF[4096,8192) BZ[8192,12288)
    // Epilogue reuse: seg = float2[32][128] at [0,32KB); hin = float[32][128] at [32KB,48KB)
    __shared__ unsigned short smem[24576];       // 48 KB
    __shared__ uint32_t vid_s;

    const int tid = threadIdx.x;
    if (tid == 0) vid_s = atomicAdd(counter, 1u);
    __syncthreads();
    const int vid   = (int)vid_s;
    const int pos   = vid >> 7;                  // 0..7  t-chunk
    const int chain = vid & 127;                 // (ni,b)
    const int b     = chain & 31;
    const int ni    = chain >> 5;
    const int h0    = ni * 128;
    const int browBase = b * TP_ + pos * 128;    // Ab2 row of tile t=0, tap0

    const int lane = tid & 63;
    const int wave = tid >> 6;
    const int wm   = wave >> 1, wn = wave & 1;
    const int lm   = lane & 15, quad = lane >> 4;

    // staging chunk ids (512 chunks/region; wave covers 128: lane, lane+64)
    const int c0 = wave * 128 + lane;
    const int c1 = c0 + 64;
    const int r0 = c0 >> 2, q0 = (c0 & 3) ^ ((r0 >> 2) & 3);
    const int r1 = c1 >> 2, q1 = (c1 & 3) ^ ((r1 >> 2) & 3);

    const unsigned short* WpF = Wp;
    const unsigned short* WpZ = Wp + 524288;

    const unsigned short* pA0 = Ab2 + (size_t)(browBase + r0) * 512 + q0 * 8;
    const unsigned short* pA1 = Ab2 + (size_t)(browBase + r1) * 512 + q1 * 8;
    const unsigned short* pF0 = WpF + (size_t)(h0 + r0) * 32 + q0 * 8;
    const unsigned short* pF1 = WpF + (size_t)(h0 + r1) * 32 + q1 * 8;
    const unsigned short* pZ0 = WpZ + (size_t)(h0 + r0) * 32 + q0 * 8;
    const unsigned short* pZ1 = WpZ + (size_t)(h0 + r1) * 32 + q1 * 8;

    unsigned short* dA0 = smem + wave * 1024;         // + s*12288
    unsigned short* dA1 = smem + wave * 1024 + 512;
    unsigned short* dF0 = smem + 4096 + wave * 1024;
    unsigned short* dF1 = smem + 4096 + wave * 1024 + 512;
    unsigned short* dZ0 = smem + 8192 + wave * 1024;
    unsigned short* dZ1 = smem + 8192 + wave * 1024 + 512;

    int offA[4], offB[4];
    #pragma unroll
    for (int r = 0; r < 4; ++r) {
        int ml = wm * 64 + r * 16 + lm;
        offA[r] = (4 * ml + (quad ^ ((ml >> 2) & 3))) * 8;
    }
    #pragma unroll
    for (int c = 0; c < 4; ++c) {
        int nl = wn * 64 + c * 16 + lm;
        offB[c] = 4096 + (4 * nl + (quad ^ ((nl >> 2) & 3))) * 8;
    }

    floatx4 accF[4][4] = {};
    floatx4 accZ[4][4] = {};

    for (int kt2 = 0; kt2 < 16; ++kt2) {
        const int tap = kt2 >> 3;
        const int i0  = (kt2 & 7) * 64;
        #pragma unroll
        for (int s = 0; s < 2; ++s) {
            const int aoff = tap * 512 + i0 + s * 32;
            const size_t woff = (size_t)(kt2 * 2 + s) * 16384;
            const int ls = s * 12288;
            GLL(pA0 + aoff, dA0 + ls);
            GLL(pA1 + aoff, dA1 + ls);
            GLL(pF0 + woff, dF0 + ls);
            GLL(pF1 + woff, dF1 + ls);
            GLL(pZ0 + woff, dZ0 + ls);
            GLL(pZ1 + woff, dZ1 + ls);
        }
        __syncthreads();

        #pragma unroll
        for (int s = 0; s < 2; ++s) {
            const int ls = s * 12288;
            bf16x8 af[4], bF[4], bZ[4];
            #pragma unroll
            for (int r = 0; r < 4; ++r) af[r] = *(const bf16x8*)(smem + ls + offA[r]);
            #pragma unroll
            for (int c = 0; c < 4; ++c) {
                bF[c] = *(const bf16x8*)(smem + ls + offB[c]);
                bZ[c] = *(const bf16x8*)(smem + ls + offB[c] + 4096);
            }
            #pragma unroll
            for (int r = 0; r < 4; ++r) {
                #pragma unroll
                for (int c = 0; c < 4; ++c) {
                    accF[r][c] = __builtin_amdgcn_mfma_f32_16x16x32_bf16(
                                    af[r], bF[c], accF[r][c], 0, 0, 0);
                    accZ[r][c] = __builtin_amdgcn_mfma_f32_16x16x32_bf16(
                                    af[r], bZ[c], accZ[r][c], 0, 0, 0);
                }
            }
        }
        __syncthreads();
    }

    // ================= epilogue: sigmoid + segment affines =================
    float bfv[4], bzv[4];
    #pragma unroll
    for (int c = 0; c < 4; ++c) {
        int hc = h0 + wn * 64 + c * 16 + lm;
        bfv[c] = biasF[hc];
        bzv[c] = biasZ[hc];
    }

    float2* seg  = (float2*)smem;                // [32][128] 32 KB
    float*  hinL = (float*)&smem[16384];         // [32][128] 16 KB

    #pragma unroll
    for (int r = 0; r < 4; ++r) {
        const int sid = wm * 16 + r * 4 + quad;  // segment of 4 t's
        #pragma unroll
        for (int c = 0; c < 4; ++c) {
            float A = 1.f, C = 0.f;
            #pragma unroll
            for (int v = 0; v < 4; ++v) {
                float f = sigm(accF[r][c][v] + bfv[c]);
                float z = sigm(accZ[r][c][v] + bzv[c]);
                accF[r][c][v] = f;               // keep f
                accZ[r][c][v] = z;               // keep z
                A *= f;
                C = fmaf(f, C - z, z);
            }
            seg[sid * 128 + wn * 64 + c * 16 + lm] = make_float2(A, C);
        }
    }
    __syncthreads();

    // block affine per h (threads 0..127), then lookback
    float At = 1.f, Ct = 0.f;
    if (tid < 128) {
        #pragma unroll 8
        for (int s = 0; s < 32; ++s) {
            float2 sc = seg[s * 128 + tid];
            Ct = fmaf(sc.x, Ct, sc.y);
            At *= sc.x;
        }
    }

    if (pos > 0) {
        if (tid == 0) {
            const uint32_t* fl = flags + (pos - 1) * 128 + chain;
            while (__hip_atomic_load(fl, __ATOMIC_ACQUIRE, __HIP_MEMORY_SCOPE_AGENT) == 0u)
                __builtin_amdgcn_s_sleep(8);
        }
        __syncthreads();
    }

    float Hin = 0.f;
    if (tid < 128) {
        if (pos > 0)
            Hin = __hip_atomic_load(&Hpub[((size_t)(pos - 1) * 128 + chain) * 128 + tid],
                                    __ATOMIC_RELAXED, __HIP_MEMORY_SCOPE_AGENT);
        float Hout = fmaf(At, Hin, Ct);
        __hip_atomic_store(&Hpub[((size_t)pos * 128 + chain) * 128 + tid], Hout,
                           __ATOMIC_RELAXED, __HIP_MEMORY_SCOPE_AGENT);
    }
    __threadfence();
    __syncthreads();
    if (tid == 0 && pos < 7)
        __hip_atomic_store(&flags[pos * 128 + chain], 1u,
                           __ATOMIC_RELEASE, __HIP_MEMORY_SCOPE_AGENT);

    // per-segment entry states
    if (tid < 128) {
        float run = Hin;
        #pragma unroll 8
        for (int s = 0; s < 32; ++s) {
            hinL[s * 128 + tid] = run;
            float2 sc = seg[s * 128 + tid];
            run = fmaf(sc.x, run, sc.y);
        }
    }
    __syncthreads();

    // replay tile from registers, write output
    const int rowBase = b * T_ + pos * 128;
    #pragma unroll
    for (int r = 0; r < 4; ++r) {
        const int sid = wm * 16 + r * 4 + quad;
        #pragma unroll
        for (int c = 0; c < 4; ++c) {
            const int hc = h0 + wn * 64 + c * 16 + lm;
            float hs = hinL[sid * 128 + (hc - h0)];
            #pragma unroll
            for (int v = 0; v < 4; ++v) {
                float f = accF[r][c][v];
                float z = accZ[r][c][v];
                hs = fmaf(f, hs - z, z);
                const size_t row = (size_t)(rowBase + wm * 64 + r * 16 + quad * 4 + v);
                out[row * H_ + hc] = hs;
            }
        }
    }
}

// ---------------------------------------------------------------------------
extern "C" void kernel_launch(void* const* d_in, const int* in_sizes, int n_in,
                              void* d_out, int out_size, void* d_ws, size_t ws_size,
                              hipStream_t stream) {
    const float* x  = (const float*)d_in[0];
    const float* Wz = (const float*)d_in[2];
    const float* bz = (const float*)d_in[3];
    const float* Wf = (const float*)d_in[4];
    const float* bf = (const float*)d_in[5];
    float* out = (float*)d_out;

    char* ws = (char*)d_ws;
    unsigned short* Ab2   = (unsigned short*)(ws);                            // 33.6 MB
    unsigned short* Wp    = (unsigned short*)(ws + (size_t)34 * 1024 * 1024); // 2 MB
    float*          Hpub  = (float*)(ws + (size_t)36 * 1024 * 1024);          // 512 KB
    uint32_t*       flags = (uint32_t*)(ws + (size_t)37 * 1024 * 1024);       // 4 KB
    uint32_t*       cnt   = flags + 1024;

    hipMemsetAsync(flags, 0, 8192, stream);   // flags + counter

    prep<<<NB_BUILD + NB_PACK, 256, 0, stream>>>(x, Wf, Wz, Ab2, Wp);

    mfma_gemm_scan<<<1024, 256, 0, stream>>>(Ab2, Wp, bf, bz, out, Hpub, flags, cnt);
}

// Round 6
// 203.171 us; speedup vs baseline: 2.1164x; 2.1164x over previous
//
#include <hip/hip_runtime.h>
#include <hip/hip_bf16.h>
#include <cstddef>
#include <cstdint>

// (B,T,I,H,K) = (32,1024,512,512,2)
#define B_  32
#define T_  1024
#define I_  512
#define H_  512
#define M_  (B_ * T_)     // 32768
#define TP_ 1025          // padded T rows (row 0 = zeros) per batch

typedef __bf16 bf16x8  __attribute__((ext_vector_type(8)));
typedef float  floatx4 __attribute__((ext_vector_type(4)));
typedef unsigned short ushort8v __attribute__((ext_vector_type(8)));
typedef unsigned long long u64;

__device__ __forceinline__ unsigned short f2bf(float f) {
    uint32_t u = __float_as_uint(f);
    return (unsigned short)((u + 0x7FFFu + ((u >> 16) & 1u)) >> 16);
}
__device__ __forceinline__ float sigm(float x) {
    return __builtin_amdgcn_rcpf(1.f + __expf(-x));
}

#define GLL(src, dst) __builtin_amdgcn_global_load_lds( \
    (const __attribute__((address_space(1))) void*)(src), \
    (__attribute__((address_space(3))) void*)(dst), 16, 0, 0)

// ---------------------------------------------------------------------------
// Prep: Ab2[b][trow][i] bf16 (trow 0 = zeros, else x[b][trow-1]);
//       Wp[gate][ksub][h][kw] bf16 (kk=ksub*32+kw, tap=kk>>9, i=kk&511).
// ---------------------------------------------------------------------------
#define NB_BUILD 8200    // 32*1025*512 / 8 / 256
#define NB_PACK  512     // 2*32*512*32 / 8 / 256

__global__ __launch_bounds__(256) void prep(const float* __restrict__ x,
                                            const float* __restrict__ Wf,
                                            const float* __restrict__ Wz,
                                            unsigned short* __restrict__ Ab2,
                                            unsigned short* __restrict__ Wp) {
    if (blockIdx.x < NB_BUILD) {
        int g = blockIdx.x * 256 + threadIdx.x;     // 2,099,200
        int idx8 = g << 3;
        int row = idx8 >> 9;                        // 0 .. 32*1025-1
        int col = idx8 & 511;
        int b    = (int)((unsigned)row / TP_);
        int trow = row - b * TP_;
        ushort8v o = {0, 0, 0, 0, 0, 0, 0, 0};
        if (trow > 0) {
            const float* src = &x[((size_t)b * T_ + (trow - 1)) * I_ + col];
            float4 v0 = *(const float4*)src;
            float4 v1 = *(const float4*)(src + 4);
            o[0] = f2bf(v0.x); o[1] = f2bf(v0.y); o[2] = f2bf(v0.z); o[3] = f2bf(v0.w);
            o[4] = f2bf(v1.x); o[5] = f2bf(v1.y); o[6] = f2bf(v1.z); o[7] = f2bf(v1.w);
        }
        *(ushort8v*)&Ab2[(size_t)idx8] = o;
    } else {
        int g = (blockIdx.x - NB_BUILD) * 256 + threadIdx.x;  // 131072
        int e8   = g << 3;
        int gate = e8 >> 19;
        int e2   = e8 & 524287;
        int ksub = e2 >> 14;
        int h    = (e2 >> 5) & 511;
        int kw0  = e2 & 31;
        const float* G = gate ? Wz : Wf;
        ushort8v o;
        #pragma unroll
        for (int j = 0; j < 8; ++j) {
            int kk  = ksub * 32 + kw0 + j;
            int tap = kk >> 9;
            int i   = kk & 511;
            o[j] = f2bf(G[h * (I_ * 2) + i * 2 + tap]);
        }
        *(ushort8v*)&Wp[(size_t)e8] = o;
    }
}

// ---------------------------------------------------------------------------
// Fused dual-gate MFMA GEMM + full scan via decoupled lookback.
// vid = atomicAdd start order; pos = vid>>7 (t-chunk of 128), chain = vid&127
// = (ni,b). Pred (lower vid) started earlier -> resident or done -> no
// deadlock. Handoff: Hpub64[pos][chain][h] = (1<<32)|float_bits via plain
// (relaxed, device-scope) atomicExch; consumer polls with atomicAdd(p,0).
// NO fences / acquire / release -> no cache invalidation (round-5 failure).
// ---------------------------------------------------------------------------
__global__ __launch_bounds__(256, 2) void mfma_gemm_scan(
        const unsigned short* __restrict__ Ab2,  // [32][1025][512]
        const unsigned short* __restrict__ Wp,   // [2][32][512][32]
        const float* __restrict__ biasF,
        const float* __restrict__ biasZ,
        float* __restrict__ out,                 // [M_][512] fp32
        u64* __restrict__ Hpub,                  // [8][128][128]
        uint32_t* __restrict__ counter) {
    // K-loop: per sub-stage s (s*12288 shorts): A[0,4096) BF[4096,8192) BZ[8192,12288)
    // Epilogue reuse: seg = float2[32][128] at [0,32KB); hinL = float[32][128] at [32KB,48KB)
    __shared__ unsigned short smem[24576];       // 48 KB
    __shared__ uint32_t vid_s;

    const int tid = threadIdx.x;
    if (tid == 0) vid_s = atomicAdd(counter, 1u);
    __syncthreads();
    const int vid   = (int)vid_s;
    const int pos   = vid >> 7;                  // 0..7  t-chunk
    const int chain = vid & 127;                 // (ni,b)
    const int b     = chain & 31;
    const int ni    = chain >> 5;
    const int h0    = ni * 128;
    const int browBase = b * TP_ + pos * 128;    // Ab2 row of tile t=0, tap0

    const int lane = tid & 63;
    const int wave = tid >> 6;
    const int wm   = wave >> 1, wn = wave & 1;
    const int lm   = lane & 15, quad = lane >> 4;

    // staging chunk ids (512 chunks/region; wave covers 128: lane, lane+64)
    const int c0 = wave * 128 + lane;
    const int c1 = c0 + 64;
    const int r0 = c0 >> 2, q0 = (c0 & 3) ^ ((r0 >> 2) & 3);
    const int r1 = c1 >> 2, q1 = (c1 & 3) ^ ((r1 >> 2) & 3);

    const unsigned short* WpF = Wp;
    const unsigned short* WpZ = Wp + 524288;

    const unsigned short* pA0 = Ab2 + (size_t)(browBase + r0) * 512 + q0 * 8;
    const unsigned short* pA1 = Ab2 + (size_t)(browBase + r1) * 512 + q1 * 8;
    const unsigned short* pF0 = WpF + (size_t)(h0 + r0) * 32 + q0 * 8;
    const unsigned short* pF1 = WpF + (size_t)(h0 + r1) * 32 + q1 * 8;
    const unsigned short* pZ0 = WpZ + (size_t)(h0 + r0) * 32 + q0 * 8;
    const unsigned short* pZ1 = WpZ + (size_t)(h0 + r1) * 32 + q1 * 8;

    unsigned short* dA0 = smem + wave * 1024;         // + s*12288
    unsigned short* dA1 = smem + wave * 1024 + 512;
    unsigned short* dF0 = smem + 4096 + wave * 1024;
    unsigned short* dF1 = smem + 4096 + wave * 1024 + 512;
    unsigned short* dZ0 = smem + 8192 + wave * 1024;
    unsigned short* dZ1 = smem + 8192 + wave * 1024 + 512;

    int offA[4], offB[4];
    #pragma unroll
    for (int r = 0; r < 4; ++r) {
        int ml = wm * 64 + r * 16 + lm;
        offA[r] = (4 * ml + (quad ^ ((ml >> 2) & 3))) * 8;
    }
    #pragma unroll
    for (int c = 0; c < 4; ++c) {
        int nl = wn * 64 + c * 16 + lm;
        offB[c] = 4096 + (4 * nl + (quad ^ ((nl >> 2) & 3))) * 8;
    }

    floatx4 accF[4][4] = {};
    floatx4 accZ[4][4] = {};

    for (int kt2 = 0; kt2 < 16; ++kt2) {
        const int tap = kt2 >> 3;
        const int i0  = (kt2 & 7) * 64;
        #pragma unroll
        for (int s = 0; s < 2; ++s) {
            const int aoff = tap * 512 + i0 + s * 32;
            const size_t woff = (size_t)(kt2 * 2 + s) * 16384;
            const int ls = s * 12288;
            GLL(pA0 + aoff, dA0 + ls);
            GLL(pA1 + aoff, dA1 + ls);
            GLL(pF0 + woff, dF0 + ls);
            GLL(pF1 + woff, dF1 + ls);
            GLL(pZ0 + woff, dZ0 + ls);
            GLL(pZ1 + woff, dZ1 + ls);
        }
        __syncthreads();

        #pragma unroll
        for (int s = 0; s < 2; ++s) {
            const int ls = s * 12288;
            bf16x8 af[4], bF[4], bZ[4];
            #pragma unroll
            for (int r = 0; r < 4; ++r) af[r] = *(const bf16x8*)(smem + ls + offA[r]);
            #pragma unroll
            for (int c = 0; c < 4; ++c) {
                bF[c] = *(const bf16x8*)(smem + ls + offB[c]);
                bZ[c] = *(const bf16x8*)(smem + ls + offB[c] + 4096);
            }
            #pragma unroll
            for (int r = 0; r < 4; ++r) {
                #pragma unroll
                for (int c = 0; c < 4; ++c) {
                    accF[r][c] = __builtin_amdgcn_mfma_f32_16x16x32_bf16(
                                    af[r], bF[c], accF[r][c], 0, 0, 0);
                    accZ[r][c] = __builtin_amdgcn_mfma_f32_16x16x32_bf16(
                                    af[r], bZ[c], accZ[r][c], 0, 0, 0);
                }
            }
        }
        __syncthreads();
    }

    // ================= epilogue: sigmoid + segment affines =================
    float bfv[4], bzv[4];
    #pragma unroll
    for (int c = 0; c < 4; ++c) {
        int hc = h0 + wn * 64 + c * 16 + lm;
        bfv[c] = biasF[hc];
        bzv[c] = biasZ[hc];
    }

    float2* seg  = (float2*)smem;                // [32][128] 32 KB
    float*  hinL = (float*)&smem[16384];         // [32][128] 16 KB

    #pragma unroll
    for (int r = 0; r < 4; ++r) {
        const int sid = wm * 16 + r * 4 + quad;  // segment of 4 t's
        #pragma unroll
        for (int c = 0; c < 4; ++c) {
            float A = 1.f, C = 0.f;
            #pragma unroll
            for (int v = 0; v < 4; ++v) {
                float f = sigm(accF[r][c][v] + bfv[c]);
                float z = sigm(accZ[r][c][v] + bzv[c]);
                accF[r][c][v] = f;               // keep f
                accZ[r][c][v] = z;               // keep z
                A *= f;
                C = fmaf(f, C - z, z);
            }
            seg[sid * 128 + wn * 64 + c * 16 + lm] = make_float2(A, C);
        }
    }
    __syncthreads();

    // per-h block affine (threads 0..127), lookback, publish, local states
    float Hin = 0.f;
    if (tid < 128) {
        float At = 1.f, Ct = 0.f;
        #pragma unroll 8
        for (int s = 0; s < 32; ++s) {
            float2 sc = seg[s * 128 + tid];
            Ct = fmaf(sc.x, Ct, sc.y);
            At *= sc.x;
        }
        if (pos > 0) {
            u64* p = &Hpub[((size_t)(pos - 1) * 128 + chain) * 128 + tid];
            u64 v;
            while (((v = atomicAdd(p, 0ull)) >> 32) == 0ull)
                __builtin_amdgcn_s_sleep(2);
            Hin = __uint_as_float((uint32_t)v);
        }
        if (pos < 7) {
            float Hout = fmaf(At, Hin, Ct);
            u64 pv = 0x100000000ull | (u64)__float_as_uint(Hout);
            atomicExch(&Hpub[((size_t)pos * 128 + chain) * 128 + tid], pv);
        }
        // per-segment entry states
        float run = Hin;
        #pragma unroll 8
        for (int s = 0; s < 32; ++s) {
            hinL[s * 128 + tid] = run;
            float2 sc = seg[s * 128 + tid];
            run = fmaf(sc.x, run, sc.y);
        }
    }
    __syncthreads();

    // replay tile from registers, write output
    const int rowBase = b * T_ + pos * 128;
    #pragma unroll
    for (int r = 0; r < 4; ++r) {
        const int sid = wm * 16 + r * 4 + quad;
        #pragma unroll
        for (int c = 0; c < 4; ++c) {
            const int hc = h0 + wn * 64 + c * 16 + lm;
            float hs = hinL[sid * 128 + (hc - h0)];
            #pragma unroll
            for (int v = 0; v < 4; ++v) {
                float f = accF[r][c][v];
                float z = accZ[r][c][v];
                hs = fmaf(f, hs - z, z);
                const size_t row = (size_t)(rowBase + wm * 64 + r * 16 + quad * 4 + v);
                out[row * H_ + hc] = hs;
            }
        }
    }
}

// ---------------------------------------------------------------------------
extern "C" void kernel_launch(void* const* d_in, const int* in_sizes, int n_in,
                              void* d_out, int out_size, void* d_ws, size_t ws_size,
                              hipStream_t stream) {
    const float* x  = (const float*)d_in[0];
    const float* Wz = (const float*)d_in[2];
    const float* bz = (const float*)d_in[3];
    const float* Wf = (const float*)d_in[4];
    const float* bf = (const float*)d_in[5];
    float* out = (float*)d_out;

    char* ws = (char*)d_ws;
    unsigned short* Ab2  = (unsigned short*)(ws);                            // 33.6 MB
    unsigned short* Wp   = (unsigned short*)(ws + (size_t)34 * 1024 * 1024); // 2 MB
    u64*            Hpub = (u64*)(ws + (size_t)36 * 1024 * 1024);            // 1 MB
    uint32_t*       cnt  = (uint32_t*)(ws + (size_t)37 * 1024 * 1024);

    // ws is re-poisoned 0xAA before every launch: zero the handoff + counter
    hipMemsetAsync(Hpub, 0, (size_t)1024 * 1024 + 4096, stream);

    prep<<<NB_BUILD + NB_PACK, 256, 0, stream>>>(x, Wf, Wz, Ab2, Wp);

    mfma_gemm_scan<<<1024, 256, 0, stream>>>(Ab2, Wp, bf, bz, out, Hpub, cnt);
}